// Round 1
// baseline (216.330 us; speedup 1.0000x reference)
//
#include <hip/hip_runtime.h>
#include <hip/hip_bf16.h>

typedef __attribute__((ext_vector_type(8))) short short8;
typedef __attribute__((ext_vector_type(4))) float f32x4;

#define B_T 200
#define B_D 128
#define WLD 136   // padded leading dim (bf16) for WbT rows -> conflict-free ds_read_b128

static __device__ __forceinline__ short f2bf(float f) {
  // round-to-nearest-even f32 -> bf16 (inputs are finite)
  unsigned u = __builtin_bit_cast(unsigned, f);
  u += 0x7fffu + ((u >> 16) & 1u);
  return (short)(u >> 16);
}
static __device__ __forceinline__ float bf2f(short s) {
  unsigned u = ((unsigned)(unsigned short)s) << 16;
  return __builtin_bit_cast(float, u);
}

__global__ __launch_bounds__(256, 4)
void ta_fused(const float* __restrict__ x,      // [B,T,D]
              const float* __restrict__ cand,   // [B,D]
              const void*  __restrict__ maskp,  // [B,T] int32 or 1-byte bool
              const float* __restrict__ W1,     // [384,128]
              const float* __restrict__ b1,     // [128]
              const float* __restrict__ ap,     // [1]
              const float* __restrict__ W2,     // [128]
              const float* __restrict__ b2p,    // [1]
              float* __restrict__ out)          // [B,D]
{
  __shared__ __align__(16) short wbt[B_D * WLD];  // WbT[j][k] bf16
  __shared__ float c_lds[B_D];
  __shared__ float w2_lds[B_D];
  __shared__ float beta_lds[B_D];
  __shared__ float part[4][B_D];                  // beta halves, then per-wave outputs
  __shared__ float scores[208];
  __shared__ float red[8];
  __shared__ int flag1b;

  const int b   = blockIdx.x;
  const int tid = threadIdx.x;
  const int lane = tid & 63;
  const int wv   = tid >> 6;
  const int l15  = lane & 15;
  const int g    = lane >> 4;

  if (tid == 0) flag1b = 0;
  __syncthreads();

  // --- phase 0: mask-dtype probe (int32 storage has all off-aligned bytes == 0)
  {
    const unsigned char* mb = (const unsigned char*)maskp;
    int local = 0;
    #pragma unroll
    for (int i = 0; i < 16; ++i) {
      int idx = tid * 16 + i;
      if ((idx & 3) != 0 && mb[idx] != 0) local = 1;
    }
    if (local) flag1b = 1;   // benign same-value race
  }
  if (tid < B_D) {
    c_lds[tid]  = cand[(size_t)b * B_D + tid];
    w2_lds[tid] = W2[tid];
  }
  __syncthreads();

  // --- phase 1: WbT[j][k] = W1a[k][j] + c[k]*W1c[k][j]  (bf16, transposed+padded)
  #pragma unroll 4
  for (int it = 0; it < 32; ++it) {
    int item = it * 256 + tid;
    int j  = item & 127;
    int kp = item >> 7;        // 0..63
    int k0 = kp * 2;
    float c0 = c_lds[k0], c1 = c_lds[k0 + 1];
    float wa0 = W1[(size_t)k0 * B_D + j];
    float wc0 = W1[(size_t)(256 + k0) * B_D + j];
    float wa1 = W1[(size_t)(k0 + 1) * B_D + j];
    float wc1 = W1[(size_t)(256 + k0 + 1) * B_D + j];
    unsigned lo = (unsigned short)f2bf(wa0 + c0 * wc0);
    unsigned hi = (unsigned short)f2bf(wa1 + c1 * wc1);
    *(unsigned*)&wbt[j * WLD + k0] = lo | (hi << 16);
  }
  // beta[j] = b1[j] + sum_k c[k]*W1b[k][j]   (split over two k-halves)
  {
    int j = tid & 127, kh = tid >> 7;
    float s = 0.f;
    const float* w1b = W1 + (size_t)(B_D + kh * 64) * B_D + j;
    for (int k = 0; k < 64; ++k) s += c_lds[kh * 64 + k] * w1b[(size_t)k * B_D];
    part[kh][j] = s;
  }
  __syncthreads();
  if (tid < B_D) beta_lds[tid] = b1[tid] + part[0][tid] + part[1][tid];
  __syncthreads();

  float betaL[8], w2L[8];
  #pragma unroll
  for (int nt = 0; nt < 8; ++nt) {
    int col = nt * 16 + l15;
    betaL[nt] = beta_lds[col];
    w2L[nt]   = w2_lds[col];
  }
  const float alpha = ap[0];
  const float b2    = b2p[0];

  // --- phase 2: GEMM h = x*Wb, fused PReLU + @W2 epilogue -> scores
  // m-tiles of 16 rows: 13 tiles (208 rows, 200 valid). wave w: tiles {w, w+4, w+8}, wave0 also 12.
  const int ntile = (wv == 0) ? 4 : 3;
  short8 af[4][4];   // A fragments held for pass 2 (x in bf16, per [tile][kstep])

  #pragma unroll
  for (int ti = 0; ti < 4; ++ti) {
    if (ti < ntile) {
      const int mt = (ti < 3) ? (wv + ti * 4) : 12;
      const int tb = mt * 16;
      int row = tb + l15; if (row > B_T - 1) row = B_T - 1;   // clamp tail (values unused)
      const float* xr = x + ((size_t)b * B_T + row) * B_D + g * 8;
      #pragma unroll
      for (int ks = 0; ks < 4; ++ks) {
        float4 f0 = *(const float4*)(xr + ks * 32);
        float4 f1 = *(const float4*)(xr + ks * 32 + 4);
        short8 t;
        t[0]=f2bf(f0.x); t[1]=f2bf(f0.y); t[2]=f2bf(f0.z); t[3]=f2bf(f0.w);
        t[4]=f2bf(f1.x); t[5]=f2bf(f1.y); t[6]=f2bf(f1.z); t[7]=f2bf(f1.w);
        af[ti][ks] = t;
      }
      float sc[4] = {0.f, 0.f, 0.f, 0.f};
      #pragma unroll
      for (int nt = 0; nt < 8; ++nt) {
        f32x4 acc = {0.f, 0.f, 0.f, 0.f};
        #pragma unroll
        for (int ks = 0; ks < 4; ++ks) {
          short8 bf = *(const short8*)&wbt[(nt * 16 + l15) * WLD + ks * 32 + g * 8];
          acc = __builtin_amdgcn_mfma_f32_16x16x32_bf16(af[ti][ks], bf, acc, 0, 0, 0);
        }
        #pragma unroll
        for (int r = 0; r < 4; ++r) {
          float h = acc[r] + betaL[nt];
          float p = (h >= 0.f) ? h : alpha * h;
          sc[r] += p * w2L[nt];
        }
      }
      #pragma unroll
      for (int r = 0; r < 4; ++r) {
        float v = sc[r];
        v += __shfl_xor(v, 1, 16);
        v += __shfl_xor(v, 2, 16);
        v += __shfl_xor(v, 4, 16);
        v += __shfl_xor(v, 8, 16);
        if (l15 == 0) scores[tb + g * 4 + r] = v + b2;   // D layout: row=(l>>4)*4+r
      }
    }
  }
  __syncthreads();

  // --- phase 3: masked softmax over t (block-wide)
  {
    const int t = tid;
    bool mk = false;
    float s = -INFINITY;
    if (t < B_T) {
      if (flag1b) mk = ((const unsigned char*)maskp)[(size_t)b * B_T + t] != 0;
      else        mk = ((const int*)maskp)[(size_t)b * B_T + t] != 0;
      if (mk) s = scores[t];
    }
    float v = s;
    #pragma unroll
    for (int m = 32; m >= 1; m >>= 1) v = fmaxf(v, __shfl_xor(v, m, 64));
    if (lane == 0) red[wv] = v;
    __syncthreads();
    float mx = fmaxf(fmaxf(red[0], red[1]), fmaxf(red[2], red[3]));
    float e = (t < B_T && mk) ? __expf(s - mx) : 0.f;
    float sv = e;
    #pragma unroll
    for (int m = 32; m >= 1; m >>= 1) sv += __shfl_xor(sv, m, 64);
    if (lane == 0) red[4 + wv] = sv;
    __syncthreads();
    float Z = red[4] + red[5] + red[6] + red[7];
    float w = e / Z;
    if (t < 208) scores[t] = w;   // t in [200,208): e==0 -> w==0
  }
  __syncthreads();

  // --- phase 4: out[b,:] = sum_t w[t]*x[t,:]  from held A fragments
  float pn[32];
  #pragma unroll
  for (int i = 0; i < 32; ++i) pn[i] = 0.f;
  #pragma unroll
  for (int ti = 0; ti < 4; ++ti) {
    if (ti < ntile) {
      const int mt = (ti < 3) ? (wv + ti * 4) : 12;
      float w = scores[mt * 16 + l15];   // A layout: row = lane&15 (tail rows have w=0)
      #pragma unroll
      for (int ks = 0; ks < 4; ++ks) {
        short8 t = af[ti][ks];
        #pragma unroll
        for (int e = 0; e < 8; ++e)
          pn[ks * 8 + e] += w * bf2f(t[e]);
      }
    }
  }
  #pragma unroll
  for (int i = 0; i < 32; ++i) {
    float v = pn[i];
    v += __shfl_xor(v, 1, 16);
    v += __shfl_xor(v, 2, 16);
    v += __shfl_xor(v, 4, 16);
    v += __shfl_xor(v, 8, 16);
    pn[i] = v;
  }
  if (l15 == 0) {
    #pragma unroll
    for (int i = 0; i < 32; ++i) {
      int col = (i >> 3) * 32 + g * 8 + (i & 7);
      part[wv][col] = pn[i];
    }
  }
  __syncthreads();
  if (tid < B_D) {
    out[(size_t)b * B_D + tid] = part[0][tid] + part[1][tid] + part[2][tid] + part[3][tid];
  }
}

extern "C" void kernel_launch(void* const* d_in, const int* in_sizes, int n_in,
                              void* d_out, int out_size, void* d_ws, size_t ws_size,
                              hipStream_t stream) {
  const float* x    = (const float*)d_in[0];
  const float* cand = (const float*)d_in[1];
  const void*  mask = d_in[2];
  const float* W1   = (const float*)d_in[3];
  const float* b1   = (const float*)d_in[4];
  const float* a    = (const float*)d_in[5];
  const float* W2   = (const float*)d_in[6];
  const float* b2   = (const float*)d_in[7];
  float* out = (float*)d_out;
  const int B = in_sizes[1] / B_D;   // candidate is [B,128]
  ta_fused<<<B, 256, 0, stream>>>(x, cand, mask, W1, b1, a, W2, b2, out);
}

// Round 2
// 167.841 us; speedup vs baseline: 1.2889x; 1.2889x over previous
//
#include <hip/hip_runtime.h>
#include <hip/hip_bf16.h>

typedef __attribute__((ext_vector_type(8))) short short8;
typedef __attribute__((ext_vector_type(4))) float f32x4;

#define B_T 200
#define B_D 128

static __device__ __forceinline__ short f2bf(float f) {
  // round-to-nearest-even f32 -> bf16 (inputs are finite)
  unsigned u = __builtin_bit_cast(unsigned, f);
  u += 0x7fffu + ((u >> 16) & 1u);
  return (short)(u >> 16);
}
static __device__ __forceinline__ float bf2f(short s) {
  unsigned u = ((unsigned)(unsigned short)s) << 16;
  return __builtin_bit_cast(float, u);
}

__global__ __launch_bounds__(512, 4)
void ta_fused(const float* __restrict__ x,      // [B,T,D]
              const float* __restrict__ cand,   // [B,D]
              const void*  __restrict__ maskp,  // [B,T] int32 or 1-byte bool
              const float* __restrict__ W1,     // [384,128]
              const float* __restrict__ b1,     // [128]
              const float* __restrict__ ap,     // [1]
              const float* __restrict__ W2,     // [128]
              const float* __restrict__ b2p,    // [1]
              float* __restrict__ out)          // [B,D]
{
  // wbt: fragment-linear bf16 layout. Element (k,j) of WbT stored at
  // ((k>>3)*128 + j)*8 + (k&7). MFMA B-frag (nt,ks,g,l15) = 16B at
  // fragment index (ks*4+g)*128 + nt*16 + l15  -> conflict-free reads,
  // consecutive-lane (j) writes -> conflict-free writes.
  __shared__ __align__(16) short wbt[B_D * B_D];
  __shared__ float c_lds[B_D];
  __shared__ float w2_lds[B_D];
  __shared__ float beta_lds[B_D];
  __shared__ float part[8][B_D];
  __shared__ float scores[208];
  __shared__ float red[16];
  __shared__ int flag1b;

  const int b    = blockIdx.x;
  const int tid  = threadIdx.x;
  const int lane = tid & 63;
  const int wv   = tid >> 6;      // 0..7
  const int l15  = lane & 15;
  const int g    = lane >> 4;     // 0..3

  if (tid == 0) flag1b = 0;
  __syncthreads();

  // --- phase 0: mask-dtype probe (int32 storage has all off-aligned bytes == 0)
  {
    const unsigned char* mb = (const unsigned char*)maskp;
    int local = 0;
    #pragma unroll
    for (int i = 0; i < 8; ++i) {
      int idx = tid * 8 + i;
      if ((idx & 3) != 0 && mb[idx] != 0) local = 1;
    }
    if (local) flag1b = 1;   // benign same-value race
  }
  if (tid < B_D) {
    c_lds[tid]  = cand[(size_t)b * B_D + tid];
    w2_lds[tid] = W2[tid];
  }
  __syncthreads();

  // --- phase 1: WbT[j][k] = W1a[k][j] + c[k]*W1c[k][j]  (bf16, fragment-linear)
  #pragma unroll 4
  for (int it = 0; it < 16; ++it) {
    int item = it * 512 + tid;   // 8192 items: (j, kp)
    int j  = item & 127;
    int kp = item >> 7;          // 0..63
    int k0 = kp * 2;
    float c0 = c_lds[k0], c1 = c_lds[k0 + 1];
    float wa0 = W1[(size_t)k0 * B_D + j];
    float wc0 = W1[(size_t)(256 + k0) * B_D + j];
    float wa1 = W1[(size_t)(k0 + 1) * B_D + j];
    float wc1 = W1[(size_t)(256 + k0 + 1) * B_D + j];
    unsigned lo = (unsigned short)f2bf(wa0 + c0 * wc0);
    unsigned hi = (unsigned short)f2bf(wa1 + c1 * wc1);
    ((unsigned*)wbt)[((k0 >> 3) * B_D + j) * 4 + ((k0 & 7) >> 1)] = lo | (hi << 16);
  }
  // beta[j] = b1[j] + sum_k c[k]*W1b[k][j]   (k split over 4 quarters)
  {
    int j = tid & 127, kh = tid >> 7;   // kh 0..3
    float s = 0.f;
    const float* w1b = W1 + (size_t)(B_D + kh * 32) * B_D + j;
    #pragma unroll 4
    for (int k = 0; k < 32; ++k) s += c_lds[kh * 32 + k] * w1b[(size_t)k * B_D];
    part[kh][j] = s;
  }
  __syncthreads();
  if (tid < B_D) beta_lds[tid] = b1[tid] + part[0][tid] + part[1][tid] + part[2][tid] + part[3][tid];
  __syncthreads();

  float betaL[8], w2L[8];
  #pragma unroll
  for (int nt = 0; nt < 8; ++nt) {
    int col = nt * 16 + l15;
    betaL[nt] = beta_lds[col];
    w2L[nt]   = w2_lds[col];
  }
  const float alpha = ap[0];
  const float b2    = b2p[0];

  // --- phase 2: GEMM h = x*Wb, fused PReLU + @W2 epilogue -> scores
  // 13 m-tiles of 16 rows. wave w: tile w, and tile 8+w if w<5.
  const int ntile = (wv < 5) ? 2 : 1;
  short8 af[2][4];   // A fragments held for pass 2 (x in bf16, [tile][kstep])

  // load + convert (both tiles) — issued ahead of MFMA for latency overlap
  #pragma unroll
  for (int ti = 0; ti < 2; ++ti) {
    if (ti < ntile) {
      const int mt = wv + ti * 8;
      int row = mt * 16 + l15; if (row > B_T - 1) row = B_T - 1;   // clamp tail
      const float* xr = x + ((size_t)b * B_T + row) * B_D + g * 8;
      #pragma unroll
      for (int ks = 0; ks < 4; ++ks) {
        float4 f0 = *(const float4*)(xr + ks * 32);
        float4 f1 = *(const float4*)(xr + ks * 32 + 4);
        short8 t;
        t[0]=f2bf(f0.x); t[1]=f2bf(f0.y); t[2]=f2bf(f0.z); t[3]=f2bf(f0.w);
        t[4]=f2bf(f1.x); t[5]=f2bf(f1.y); t[6]=f2bf(f1.z); t[7]=f2bf(f1.w);
        af[ti][ks] = t;
      }
    }
  }
  #pragma unroll
  for (int ti = 0; ti < 2; ++ti) {
    if (ti < ntile) {
      const int mt = wv + ti * 8;
      const int tb = mt * 16;
      float sc[4] = {0.f, 0.f, 0.f, 0.f};
      #pragma unroll
      for (int nt = 0; nt < 8; ++nt) {
        f32x4 acc = {0.f, 0.f, 0.f, 0.f};
        #pragma unroll
        for (int ks = 0; ks < 4; ++ks) {
          short8 bf = *(const short8*)&wbt[(((ks * 4 + g) * B_D) + nt * 16 + l15) * 8];
          acc = __builtin_amdgcn_mfma_f32_16x16x32_bf16(af[ti][ks], bf, acc, 0, 0, 0);
        }
        #pragma unroll
        for (int r = 0; r < 4; ++r) {
          float h = acc[r] + betaL[nt];
          float p = (h >= 0.f) ? h : alpha * h;
          sc[r] += p * w2L[nt];
        }
      }
      #pragma unroll
      for (int r = 0; r < 4; ++r) {
        float v = sc[r];
        v += __shfl_xor(v, 1, 16);
        v += __shfl_xor(v, 2, 16);
        v += __shfl_xor(v, 4, 16);
        v += __shfl_xor(v, 8, 16);
        if (l15 == 0) scores[tb + g * 4 + r] = v + b2;   // D layout: row=(l>>4)*4+r
      }
    }
  }
  __syncthreads();

  // --- phase 3: masked softmax over t (block-wide, all 8 waves uniform)
  {
    const int t = tid;
    bool mk = false;
    float s = -INFINITY;
    if (t < B_T) {
      if (flag1b) mk = ((const unsigned char*)maskp)[(size_t)b * B_T + t] != 0;
      else        mk = ((const int*)maskp)[(size_t)b * B_T + t] != 0;
      if (mk) s = scores[t];
    }
    float v = s;
    #pragma unroll
    for (int m = 32; m >= 1; m >>= 1) v = fmaxf(v, __shfl_xor(v, m, 64));
    if (lane == 0) red[wv] = v;
    __syncthreads();
    float mx = -INFINITY;
    #pragma unroll
    for (int i = 0; i < 8; ++i) mx = fmaxf(mx, red[i]);
    float e = (t < B_T && mk) ? __expf(s - mx) : 0.f;
    float sv = e;
    #pragma unroll
    for (int m = 32; m >= 1; m >>= 1) sv += __shfl_xor(sv, m, 64);
    if (lane == 0) red[8 + wv] = sv;
    __syncthreads();
    float Z = 0.f;
    #pragma unroll
    for (int i = 0; i < 8; ++i) Z += red[8 + i];
    float w = e / Z;
    if (t < 208) scores[t] = w;   // t in [200,208): e==0 -> w==0
  }
  __syncthreads();

  // --- phase 4: out[b,:] = sum_t w[t]*x[t,:] from held A fragments (per-ks)
  {
    float w0 = scores[(wv + 0 * 8) * 16 + l15];
    float w1 = (ntile > 1) ? scores[(wv + 1 * 8) * 16 + l15] : 0.f;
    #pragma unroll
    for (int ks = 0; ks < 4; ++ks) {
      float accw[8];
      #pragma unroll
      for (int e = 0; e < 8; ++e) accw[e] = 0.f;
      {
        short8 t0 = af[0][ks];
        #pragma unroll
        for (int e = 0; e < 8; ++e) accw[e] += w0 * bf2f(t0[e]);
      }
      if (ntile > 1) {
        short8 t1 = af[1][ks];
        #pragma unroll
        for (int e = 0; e < 8; ++e) accw[e] += w1 * bf2f(t1[e]);
      }
      #pragma unroll
      for (int e = 0; e < 8; ++e) {
        float v = accw[e];
        v += __shfl_xor(v, 1, 16);
        v += __shfl_xor(v, 2, 16);
        v += __shfl_xor(v, 4, 16);
        v += __shfl_xor(v, 8, 16);
        if (l15 == 0) part[wv][ks * 32 + g * 8 + e] = v;
      }
    }
  }
  __syncthreads();
  if (tid < B_D) {
    float s = 0.f;
    #pragma unroll
    for (int i = 0; i < 8; ++i) s += part[i][tid];
    out[(size_t)b * B_D + tid] = s;
  }
}

extern "C" void kernel_launch(void* const* d_in, const int* in_sizes, int n_in,
                              void* d_out, int out_size, void* d_ws, size_t ws_size,
                              hipStream_t stream) {
  const float* x    = (const float*)d_in[0];
  const float* cand = (const float*)d_in[1];
  const void*  mask = d_in[2];
  const float* W1   = (const float*)d_in[3];
  const float* b1   = (const float*)d_in[4];
  const float* a    = (const float*)d_in[5];
  const float* W2   = (const float*)d_in[6];
  const float* b2   = (const float*)d_in[7];
  float* out = (float*)d_out;
  const int B = in_sizes[1] / B_D;   // candidate is [B,128]
  ta_fused<<<B, 512, 0, stream>>>(x, cand, mask, W1, b1, a, W2, b2, out);
}